// Round 15
// baseline (88.351 us; speedup 1.0000x reference)
//
#include <hip/hip_runtime.h>
#include <stdint.h>

typedef unsigned short u16;
typedef __attribute__((ext_vector_type(8))) __bf16 bf16x8;
typedef __attribute__((ext_vector_type(4))) float f32x4;
typedef __attribute__((ext_vector_type(16))) float f32x16;

#define D_IN 1024
#define NH 16
#define DH 64
#define BATCH 2
#define SEQ 2048

// log2(e)/sqrt(64): folded into Q at the QKV-projection epilogue so the
// attention kernel can use v_exp_f32 (2^x) directly with NO per-score scaling.
#define QSCL 0.1803368801111244f

#define GLD_LDS16(gp, lp)                                                              \
  __builtin_amdgcn_global_load_lds((__attribute__((address_space(1))) const void*)(gp), \
                                   (__attribute__((address_space(3))) void*)(lp), 16, 0, 0)

__device__ __forceinline__ u16 f2b(float f) {
  union { float ff; uint32_t u; } v; v.ff = f;
  return (u16)((v.u + 0x7fffu + ((v.u >> 16) & 1u)) >> 16);
}

__device__ __forceinline__ float swap32f(float v) { return __shfl_xor(v, 32, 64); }

__device__ __forceinline__ uint32_t cvtpk(float a, float b) {
  uint32_t r;
  asm("v_cvt_pk_bf16_f32 %0, %1, %2" : "=v"(r) : "v"(a), "v"(b));
  return r;
}
__device__ __forceinline__ float fexp2(float x) {
  float r;
  asm("v_exp_f32 %0, %1" : "=v"(r) : "v"(x));
  return r;
}

// ---------------- 1) fused prep: x->bf16  +  W->W^T bf16 ----------------
__global__ __launch_bounds__(256)
void prep_kernel(const float* __restrict__ x, u16* __restrict__ xb,
                 const float* __restrict__ W0, const float* __restrict__ W1,
                 const float* __restrict__ W2, const float* __restrict__ W3,
                 u16* __restrict__ T0, u16* __restrict__ T1,
                 u16* __restrict__ T2, u16* __restrict__ T3) {
  __shared__ float tile[32][33];
  if (blockIdx.x < 4096) {
    const int i = (blockIdx.x * 256 + threadIdx.x) * 4;
    const float4 v = *(const float4*)(x + i);
    uint2 pack;
    pack.x = (uint32_t)f2b(v.x) | ((uint32_t)f2b(v.y) << 16);
    pack.y = (uint32_t)f2b(v.z) | ((uint32_t)f2b(v.w) << 16);
    *(uint2*)(xb + i) = pack;
  } else {
    const int bid2 = blockIdx.x - 4096;
    const float* W; u16* T;
    switch (bid2 >> 10) {
      case 0: W = W0; T = T0; break;
      case 1: W = W1; T = T1; break;
      case 2: W = W2; T = T2; break;
      default: W = W3; T = T3; break;
    }
    const int rem = bid2 & 1023;
    const int n0 = (rem >> 5) * 32, k0 = (rem & 31) * 32;
    const int tx = threadIdx.x & 31, ty = threadIdx.x >> 5;
    #pragma unroll
    for (int i = 0; i < 32; i += 8)
      tile[ty + i][tx] = W[(size_t)(k0 + ty + i) * D_IN + n0 + tx];
    __syncthreads();
    #pragma unroll
    for (int i = 0; i < 32; i += 8)
      T[(size_t)(n0 + ty + i) * D_IN + k0 + tx] = f2b(tile[tx][ty + i]);
  }
}

// ---------------- 2) FUSED QKV projection GEMM (r14, unchanged) ----------------
__device__ __forceinline__ void qkv_compute(
    const u16* __restrict__ AsB, const u16* __restrict__ Bq,
    const u16* __restrict__ Bk, const u16* __restrict__ Bv,
    int wm, int wn, int g, int lm,
    f32x4 accq[4][2], f32x4 acck[4][2], f32x4 accv[4][2]) {
  #pragma unroll
  for (int kk = 0; kk < 2; ++kk) {
    const int slot = ((kk * 4 + g) ^ (lm & 7)) << 3;
    bf16x8 af[4];
    #pragma unroll
    for (int i = 0; i < 4; ++i)
      af[i] = *(const bf16x8*)(AsB + (wm * 64 + i * 16 + lm) * 64 + slot);
    bf16x8 bq[2], bk[2], bv[2];
    #pragma unroll
    for (int n = 0; n < 2; ++n) {
      const int ro = (wn * 32 + n * 16 + lm) * 64 + slot;
      bq[n] = *(const bf16x8*)(Bq + ro);
      bk[n] = *(const bf16x8*)(Bk + ro);
      bv[n] = *(const bf16x8*)(Bv + ro);
    }
    #pragma unroll
    for (int i = 0; i < 4; ++i)
      #pragma unroll
      for (int n = 0; n < 2; ++n) {
        accq[i][n] = __builtin_amdgcn_mfma_f32_16x16x32_bf16(af[i], bq[n], accq[i][n], 0, 0, 0);
        acck[i][n] = __builtin_amdgcn_mfma_f32_16x16x32_bf16(af[i], bk[n], acck[i][n], 0, 0, 0);
        accv[i][n] = __builtin_amdgcn_mfma_f32_16x16x32_bf16(af[i], bv[n], accv[i][n], 0, 0, 0);
      }
  }
}

__global__ __launch_bounds__(512)
void gemm_qkv_kernel(const u16* __restrict__ Xb,
                     const u16* __restrict__ WqT, const u16* __restrict__ WkT,
                     const u16* __restrict__ WvT,
                     u16* __restrict__ Qo, u16* __restrict__ Ko, u16* __restrict__ Vt) {
  __shared__ u16 smem[65536];          // 128 KB: As[2] | Bs[2][3]
  u16* As0 = smem;                     // As[buf] = As0 + buf*8192
  u16* Bs0 = smem + 16384;             // Bs[buf][wh] = Bs0 + buf*24576 + wh*8192

  const int tid = threadIdx.x;
  const int lane = tid & 63;
  const int w = tid >> 6;            // 0..7
  const int wm = w >> 2, wn = w & 3; // wave tile 64x32 per which
  const int bm = blockIdx.x * 128;
  const int bn = blockIdx.y * 128;
  const int g = lane >> 4, lm = lane & 15;

  const int r_in = lane >> 3;
  const int s_w = lane & 7;
  const int swz_col = (s_w ^ r_in) << 3;

  const int c0 = w * 2;  // this wave's chunk base (2 chunks of 8 rows each)
  const u16* a_src0 = Xb + (size_t)(bm + c0 * 8 + r_in) * D_IN + swz_col;
  const u16* a_src1 = a_src0 + 8 * D_IN;
  const u16* q_src0 = WqT + (size_t)(bn + c0 * 8 + r_in) * D_IN + swz_col;
  const u16* q_src1 = q_src0 + 8 * D_IN;
  const u16* k_src0 = WkT + (size_t)(bn + c0 * 8 + r_in) * D_IN + swz_col;
  const u16* k_src1 = k_src0 + 8 * D_IN;
  const u16* v_src0 = WvT + (size_t)(bn + c0 * 8 + r_in) * D_IN + swz_col;
  const u16* v_src1 = v_src0 + 8 * D_IN;

#define QKV_STAGE(BUF, K0)                                            \
  do {                                                                \
    GLD_LDS16(a_src0 + (K0), As0 + (BUF)*8192 + c0 * 512);            \
    GLD_LDS16(a_src1 + (K0), As0 + (BUF)*8192 + c0 * 512 + 512);      \
    GLD_LDS16(q_src0 + (K0), Bs0 + (BUF)*24576 + c0 * 512);           \
    GLD_LDS16(q_src1 + (K0), Bs0 + (BUF)*24576 + c0 * 512 + 512);     \
    GLD_LDS16(k_src0 + (K0), Bs0 + (BUF)*24576 + 8192 + c0 * 512);    \
    GLD_LDS16(k_src1 + (K0), Bs0 + (BUF)*24576 + 8192 + c0 * 512 + 512); \
    GLD_LDS16(v_src0 + (K0), Bs0 + (BUF)*24576 + 16384 + c0 * 512);   \
    GLD_LDS16(v_src1 + (K0), Bs0 + (BUF)*24576 + 16384 + c0 * 512 + 512); \
  } while (0)

  f32x4 accq[4][2], acck[4][2], accv[4][2];
  #pragma unroll
  for (int i = 0; i < 4; ++i)
    #pragma unroll
    for (int n = 0; n < 2; ++n) {
      accq[i][n] = {0.f, 0.f, 0.f, 0.f};
      acck[i][n] = {0.f, 0.f, 0.f, 0.f};
      accv[i][n] = {0.f, 0.f, 0.f, 0.f};
    }

  QKV_STAGE(0, 0);
  QKV_STAGE(1, 64);
  #pragma unroll 1
  for (int tt = 0; tt < 7; ++tt) {
    asm volatile("s_waitcnt vmcnt(8)" ::: "memory");
    __builtin_amdgcn_s_barrier();
    qkv_compute(As0, Bs0, Bs0 + 8192, Bs0 + 16384, wm, wn, g, lm, accq, acck, accv);
    __builtin_amdgcn_s_barrier();
    QKV_STAGE(0, (2 * tt + 2) * 64);
    asm volatile("s_waitcnt vmcnt(8)" ::: "memory");
    __builtin_amdgcn_s_barrier();
    qkv_compute(As0 + 8192, Bs0 + 24576, Bs0 + 32768, Bs0 + 40960, wm, wn, g, lm,
                accq, acck, accv);
    __builtin_amdgcn_s_barrier();
    QKV_STAGE(1, (2 * tt + 3) * 64);
  }
  asm volatile("s_waitcnt vmcnt(8)" ::: "memory");
  __builtin_amdgcn_s_barrier();
  qkv_compute(As0, Bs0, Bs0 + 8192, Bs0 + 16384, wm, wn, g, lm, accq, acck, accv);  // t=14
  asm volatile("s_waitcnt vmcnt(0)" ::: "memory");
  __builtin_amdgcn_s_barrier();
  qkv_compute(As0 + 8192, Bs0 + 24576, Bs0 + 32768, Bs0 + 40960, wm, wn, g, lm,
              accq, acck, accv);  // t=15
#undef QKV_STAGE

  // ---- epilogue: LDS repack -> coalesced fragment stores ----
  __syncthreads();                       // staging LDS now safely reusable
  u16* pool = smem + w * 6144;           // 12 KB per wave: Q[0,2048) K[2048,4096) V[4096,6144)
  const int M0 = bm + wm * 64;
  const int T0v = (M0 & (SEQ - 1)) >> 5; // WITHIN-BATCH tile base (r13 bug fixed)
  const int C0 = bn + wn * 32;
  const int D0 = C0 & 63;                // 0 or 32
  const int S0 = D0 >> 4;                // st base (0 or 2)
  const int d5 = D0 >> 5;                // 0 or 1
  const int bh = (M0 >> 11) * NH + (C0 >> 6);

  #pragma unroll
  for (int i = 0; i < 4; ++i) {
    const int ti = i >> 1;
    const int nbase = (i & 1) * 16 + g * 4;          // nn&31, minus r
    #pragma unroll
    for (int n = 0; n < 2; ++n) {
      #pragma unroll
      for (int r = 0; r < 4; ++r) {
        // Q/K: lane2 = ((d>>3)&1)*32 + (nn&31); j = d&7
        const int offqk = (ti * 2 + n) * 512 + (((lm >> 3) << 5) + nbase + r) * 8 + (lm & 7);
        pool[offqk] = f2b(accq[i][n][r] * QSCL);
        pool[2048 + offqk] = f2b(acck[i][n][r]);
        // V: lane2 = (g&1)*32 + (d&31); j = (g>>1)*4 + r; frag slot = ti*2 + (i&1)
        const int offv = 4096 + (ti * 2 + (i & 1)) * 512 +
                         ((g & 1) * 32 + n * 16 + lm) * 8 + ((g >> 1) << 2) + r;
        pool[offv] = f2b(accv[i][n][r]);
      }
    }
  }
  asm volatile("s_waitcnt lgkmcnt(0)" ::: "memory");
  #pragma unroll
  for (int fl = 0; fl < 4; ++fl) {
    const int t = T0v + (fl >> 1);
    const int st = S0 + (fl & 1);
    const uint4 vq = *(const uint4*)(pool + fl * 512 + lane * 8);
    *(uint4*)(Qo + ((size_t)(bh * 64 + t) * 4 + st) * 512 + lane * 8) = vq;
    const uint4 vk = *(const uint4*)(pool + 2048 + fl * 512 + lane * 8);
    *(uint4*)(Ko + ((size_t)(bh * 64 + t) * 4 + st) * 512 + lane * 8) = vk;
    const int f = ((fl & 1) << 1) + d5;
    const uint4 vv = *(const uint4*)(pool + 4096 + fl * 512 + lane * 8);
    *(uint4*)(Vt + ((size_t)(bh * 64 + t) * 4 + f) * 512 + lane * 8) = vv;
  }
}

// ---------------- 3) causal flash attention: fixed-max, 4-way split-k ----------------
// r10 structure; NEW: QK^T split into TWO independent accumulator chains
// (sa, sb) -- halves the serial MFMA dependency depth (the dominant per-tile
// latency; attn measures ~3x its issue floor). Sum before exp (16 VALU adds).
__global__ __launch_bounds__(256)
void attn4_kernel(const u16* __restrict__ Qb, const u16* __restrict__ Kb,
                  const u16* __restrict__ Vt, u16* __restrict__ Ctx) {
  __shared__ float mbuf[4][32][64];   // [wave][q][d], chunk-XOR-swizzled
  __shared__ float lbuf[4][32];

  const int tid = threadIdx.x;
  const int lane = tid & 63;
  const int kw = tid >> 6;             // wave = split-k slot 0..3
  const int ql = lane & 31;
  const int hi = lane >> 5;
  const int bid = blockIdx.x;
  const int c = bid & 7;
  const int r = bid >> 3;              // 0..127
  const int jj = r & 31;               // pair index
  const int bh = c + 8 * (r >> 5);     // 0..31
  const int b = bh >> 4, h = bh & 15;

  const u16* Qf = Qb + (size_t)bh * 64 * 2048;
  const u16* Kf = Kb + (size_t)bh * 64 * 2048;
  const u16* Vf = Vt + (size_t)bh * 64 * 2048;
  const int lofs = lane * 8;

  #pragma unroll 1
  for (int pass = 0; pass < 2; ++pass) {
    const int qt = pass ? (63 - jj) : jj;
    const int qb0 = qt * 32;

    bf16x8 qf[4];
    {
      const u16* qp = Qf + (size_t)qt * 2048 + lofs;
      #pragma unroll
      for (int st = 0; st < 4; ++st) qf[st] = *(const bf16x8*)(qp + st * 512);
    }

    f32x16 ctx0 = {0,0,0,0,0,0,0,0,0,0,0,0,0,0,0,0};
    f32x16 ctx1 = {0,0,0,0,0,0,0,0,0,0,0,0,0,0,0,0};
    float lacc[4] = {0.f, 0.f, 0.f, 0.f};

    bf16x8 kf[4], vf[4];
    if (kw <= qt) {
      // prologue load: tile kw
      {
        const u16* kp = Kf + (size_t)kw * 2048 + lofs;
        const u16* vp = Vf + (size_t)kw * 2048 + lofs;
        #pragma unroll
        for (int st = 0; st < 4; ++st) kf[st] = *(const bf16x8*)(kp + st * 512);
        #pragma unroll
        for (int f = 0; f < 4; ++f) vf[f] = *(const bf16x8*)(vp + f * 512);
      }
      #pragma unroll 2
      for (int t = kw; t <= qt; t += 4) {
        // ---- QK^T: two independent accumulator chains ----
        f32x16 sa = {0,0,0,0,0,0,0,0,0,0,0,0,0,0,0,0};
        f32x16 sb = {0,0,0,0,0,0,0,0,0,0,0,0,0,0,0,0};
        sa = __builtin_amdgcn_mfma_f32_32x32x16_bf16(kf[0], qf[0], sa, 0, 0, 0);
        sb = __builtin_amdgcn_mfma_f32_32x32x16_bf16(kf[2], qf[2], sb, 0, 0, 0);
        sa = __builtin_amdgcn_mfma_f32_32x32x16_bf16(kf[1], qf[1], sa, 0, 0, 0);
        sb = __builtin_amdgcn_mfma_f32_32x32x16_bf16(kf[3], qf[3], sb, 0, 0, 0);

        // prefetch next tile's K (kf dead after QK); clamped reload on last iter
        const int tn = (t + 4 <= qt) ? (t + 4) : qt;
        {
          const u16* kp = Kf + (size_t)tn * 2048 + lofs;
          #pragma unroll
          for (int st = 0; st < 4; ++st) kf[st] = *(const bf16x8*)(kp + st * 512);
        }

        // ---- softmax (fixed max = 0) ----
        float p[16];
        if (t == qt) {  // diagonal tile: causal mask (wave-uniform branch)
          #pragma unroll
          for (int cr = 0; cr < 16; ++cr) {
            const int kl = ((cr & 3) + 8 * (cr >> 2)) + 4 * hi;
            p[cr] = (kl > ql) ? 0.f : fexp2(sa[cr] + sb[cr]);
          }
        } else {
          #pragma unroll
          for (int cr = 0; cr < 16; ++cr) p[cr] = fexp2(sa[cr] + sb[cr]);
        }
        #pragma unroll
        for (int cr = 0; cr < 16; ++cr) lacc[cr & 3] += p[cr];

        // ---- PV: fragment k-order baked into V's stored layout ----
        #pragma unroll
        for (int ks = 0; ks < 2; ++ks) {
          uint4 pw;
          pw.x = cvtpk(p[ks * 8 + 0], p[ks * 8 + 1]);
          pw.y = cvtpk(p[ks * 8 + 2], p[ks * 8 + 3]);
          pw.z = cvtpk(p[ks * 8 + 4], p[ks * 8 + 5]);
          pw.w = cvtpk(p[ks * 8 + 6], p[ks * 8 + 7]);
          union { uint4 u; bf16x8 v; } pa; pa.u = pw;
          ctx0 = __builtin_amdgcn_mfma_f32_32x32x16_bf16(vf[ks * 2 + 0], pa.v, ctx0, 0, 0, 0);
          ctx1 = __builtin_amdgcn_mfma_f32_32x32x16_bf16(vf[ks * 2 + 1], pa.v, ctx1, 0, 0, 0);
        }

        // prefetch next tile's V (vf dead after PV)
        {
          const u16* vp = Vf + (size_t)tn * 2048 + lofs;
          #pragma unroll
          for (int f = 0; f < 4; ++f) vf[f] = *(const bf16x8*)(vp + f * 512);
        }
      }
    }

    // ---- 4-way split-k merge (fixed max -> pure addition) ----
    const float lloc = (lacc[0] + lacc[1]) + (lacc[2] + lacc[3]);
    const float lwv = lloc + swap32f(lloc);

    // write partial ctx: chunk ch = d/4, stored at ch ^ (q&15) (bank-conflict-free)
    #pragma unroll
    for (int grp = 0; grp < 4; ++grp) {
      const int ch = grp * 2 + hi;
      f32x4 t0 = {ctx0[grp * 4 + 0], ctx0[grp * 4 + 1], ctx0[grp * 4 + 2], ctx0[grp * 4 + 3]};
      f32x4 t1 = {ctx1[grp * 4 + 0], ctx1[grp * 4 + 1], ctx1[grp * 4 + 2], ctx1[grp * 4 + 3]};
      *(f32x4*)&mbuf[kw][ql][(ch ^ ql) * 4 & 63]       = t0;
      *(f32x4*)&mbuf[kw][ql][((ch + 8) ^ ql) * 4 & 63] = t1;
    }
    if (lane < 32) lbuf[kw][ql] = lwv;
    __syncthreads();

    // each wave sums d-slice [kw*16 + hi*8, +8) over the 4 partials
    {
      const int ch0 = kw * 4 + hi * 2;
      f32x4 a0 = {0.f, 0.f, 0.f, 0.f}, a1 = {0.f, 0.f, 0.f, 0.f};
      #pragma unroll
      for (int p2 = 0; p2 < 4; ++p2) {
        a0 += *(const f32x4*)&mbuf[p2][ql][(ch0 ^ ql) * 4 & 63];
        a1 += *(const f32x4*)&mbuf[p2][ql][((ch0 + 1) ^ ql) * 4 & 63];
      }
      const float lt = (lbuf[0][ql] + lbuf[1][ql]) + (lbuf[2][ql] + lbuf[3][ql]);
      const float inv = __builtin_amdgcn_rcpf(lt);
      uint4 pw;
      pw.x = cvtpk(a0[0] * inv, a0[1] * inv);
      pw.y = cvtpk(a0[2] * inv, a0[3] * inv);
      pw.z = cvtpk(a1[0] * inv, a1[1] * inv);
      pw.w = cvtpk(a1[2] * inv, a1[3] * inv);
      *(uint4*)(Ctx + (size_t)(b * SEQ + qb0 + ql) * 1024 + h * 64 + kw * 16 + hi * 8) = pw;
    }
    __syncthreads();  // protect mbuf/lbuf reuse in next pass
  }
}

// ---------------- 4) output projection + bias (fp32 out) ----------------
// TM=64 -> grid (64,8) = 512 blocks = 2 blocks/CU (r14 was 1/CU: 4 waves in
// barrier lockstep, staging drain fully exposed). LDS 48 KB. Counted-vmcnt
// pipeline kept; 6 GLD/wave/stage -> vmcnt(6).
__device__ __forceinline__ void out_compute(
    const u16* __restrict__ AsB, const u16* __restrict__ BsB,
    int wr, int wc, int g, int lm, f32x4 acc[2][4]) {
  #pragma unroll
  for (int kk = 0; kk < 2; ++kk) {
    const int slot = ((kk * 4 + g) ^ (lm & 7)) << 3;
    bf16x8 af[2], bf[4];
    #pragma unroll
    for (int i = 0; i < 2; ++i)
      af[i] = *(const bf16x8*)(AsB + (wr * 32 + i * 16 + lm) * 64 + slot);
    #pragma unroll
    for (int n = 0; n < 4; ++n)
      bf[n] = *(const bf16x8*)(BsB + (wc * 64 + n * 16 + lm) * 64 + slot);
    #pragma unroll
    for (int i = 0; i < 2; ++i)
      #pragma unroll
      for (int n = 0; n < 4; ++n)
        acc[i][n] = __builtin_amdgcn_mfma_f32_16x16x32_bf16(af[i], bf[n], acc[i][n], 0, 0, 0);
  }
}

__global__ __launch_bounds__(256)
void gemm_out_kernel(const u16* __restrict__ Ctx, const u16* __restrict__ WoT,
                     const float* __restrict__ bo, float* __restrict__ out) {
  __shared__ u16 As[2][64 * 64];   // 8 KB each
  __shared__ u16 Bs[2][128 * 64];  // 16 KB each
  const int tid = threadIdx.x;
  const int lane = tid & 63;
  const int w = tid >> 6;
  const int bm = blockIdx.x * 64;
  const int bn = blockIdx.y * 128;
  const int wr = w >> 1, wc = w & 1;
  const int g = lane >> 4, lm = lane & 15;

  const int r_in = lane >> 3;
  const int s_w = lane & 7;
  const int swz_col = (s_w ^ r_in) << 3;

  // A: wave stages rows [w*16, w*16+16) -> 2 GLD; B: rows [w*32, w*32+32) -> 4 GLD
  const u16* a_src = Ctx + (size_t)(bm + w * 16 + r_in) * D_IN + swz_col;
  const u16* b_src = WoT + (size_t)(bn + w * 32 + r_in) * D_IN + swz_col;

#define OUT_STAGE(BUF, K0)                                                  \
  do {                                                                      \
    GLD_LDS16(a_src + (K0), &As[BUF][(w * 2) * 512]);                       \
    GLD_LDS16(a_src + 8 * D_IN + (K0), &As[BUF][(w * 2 + 1) * 512]);        \
    _Pragma("unroll")                                                       \
    for (int j = 0; j < 4; ++j)                                             \
      GLD_LDS16(b_src + j * 8 * D_IN + (K0), &Bs[BUF][(w * 4 + j) * 512]);  \
  } while (0)

  f32x4 acc[2][4];
  #pragma unroll
  for (int i = 0; i < 2; ++i)
    #pragma unroll
    for (int n = 0; n < 4; ++n) acc[i][n] = {0.f, 0.f, 0.f, 0.f};

  OUT_STAGE(0, 0);
  OUT_STAGE(1, 64);
  #pragma unroll 1
  for (int tt = 0; tt < 7; ++tt) {
    asm volatile("s_waitcnt vmcnt(6)" ::: "memory");
    __builtin_amdgcn_s_barrier();
    out_compute(As[0], Bs[0], wr, wc, g, lm, acc);
    __builtin_amdgcn_s_barrier();
    OUT_STAGE(0, (2 * tt + 2) * 64);
    asm volatile("s_waitcnt vmcnt(6)" ::: "memory");
    __builtin_amdgcn_s_barrier();
    out_compute(As[1], Bs[1], wr, wc, g, lm, acc);
    __builtin_amdgcn_s_barrier();
    OUT_STAGE(1, (2 * tt + 3) * 64);
  }
  asm volatile("s_waitcnt vmcnt(6)" ::: "memory");
  __builtin_amdgcn_s_barrier();
  out_compute(As[0], Bs[0], wr, wc, g, lm, acc);  // t=14
  asm volatile("s_waitcnt vmcnt(0)" ::: "memory");
  __builtin_amdgcn_s_barrier();
  out_compute(As[1], Bs[1], wr, wc, g, lm, acc);  // t=15
#undef OUT_STAGE

  #pragma unroll
  for (int i = 0; i < 2; ++i)
    #pragma unroll
    for (int n = 0; n < 4; ++n)
      #pragma unroll
      for (int r = 0; r < 4; ++r) {
        const int m = bm + wr * 32 + i * 16 + g * 4 + r;
        const int cidx = bn + wc * 64 + n * 16 + lm;
        out[(size_t)m * 1024 + cidx] = acc[i][n][r] + bo[cidx];
      }
}

extern "C" void kernel_launch(void* const* d_in, const int* in_sizes, int n_in,
                              void* d_out, int out_size, void* d_ws, size_t ws_size,
                              hipStream_t stream) {
  (void)in_sizes; (void)n_in; (void)out_size; (void)ws_size;
  const float* x  = (const float*)d_in[0];
  const float* Wq = (const float*)d_in[1];
  const float* Wk = (const float*)d_in[2];
  const float* Wv = (const float*)d_in[3];
  const float* Wo = (const float*)d_in[4];
  const float* bo = (const float*)d_in[5];
  float* out = (float*)d_out;

  char* ws = (char*)d_ws;
  u16* xb  = (u16*)(ws);
  u16* WqT = (u16*)(ws + (8u << 20));
  u16* WkT = (u16*)(ws + (10u << 20));
  u16* WvT = (u16*)(ws + (12u << 20));
  u16* WoT = (u16*)(ws + (14u << 20));
  u16* Qb  = (u16*)(ws + (16u << 20));
  u16* Kb  = (u16*)(ws + (24u << 20));
  u16* Vt  = (u16*)(ws + (32u << 20));
  u16* Ctx = xb;  // xb fully consumed by gemm_qkv before attn writes Ctx

  prep_kernel<<<dim3(8192), 256, 0, stream>>>(x, xb, Wq, Wk, Wv, Wo, WqT, WkT, WvT, WoT);
  gemm_qkv_kernel<<<dim3(32, 8), 512, 0, stream>>>(xb, WqT, WkT, WvT, Qb, Kb, Vt);
  attn4_kernel<<<dim3(1024), 256, 0, stream>>>(Qb, Kb, Vt, Ctx);
  gemm_out_kernel<<<dim3(64, 8), 256, 0, stream>>>(Ctx, WoT, bo, out);
}

// Round 16
// 83.703 us; speedup vs baseline: 1.0555x; 1.0555x over previous
//
#include <hip/hip_runtime.h>
#include <stdint.h>

typedef unsigned short u16;
typedef __attribute__((ext_vector_type(8))) __bf16 bf16x8;
typedef __attribute__((ext_vector_type(4))) float f32x4;
typedef __attribute__((ext_vector_type(16))) float f32x16;

#define D_IN 1024
#define NH 16
#define DH 64
#define BATCH 2
#define SEQ 2048

// log2(e)/sqrt(64): folded into Q at the QKV-projection epilogue so the
// attention kernel can use v_exp_f32 (2^x) directly with NO per-score scaling.
#define QSCL 0.1803368801111244f

#define GLD_LDS16(gp, lp)                                                              \
  __builtin_amdgcn_global_load_lds((__attribute__((address_space(1))) const void*)(gp), \
                                   (__attribute__((address_space(3))) void*)(lp), 16, 0, 0)

__device__ __forceinline__ u16 f2b(float f) {
  union { float ff; uint32_t u; } v; v.ff = f;
  return (u16)((v.u + 0x7fffu + ((v.u >> 16) & 1u)) >> 16);
}

__device__ __forceinline__ float swap32f(float v) { return __shfl_xor(v, 32, 64); }

__device__ __forceinline__ uint32_t cvtpk(float a, float b) {
  uint32_t r;
  asm("v_cvt_pk_bf16_f32 %0, %1, %2" : "=v"(r) : "v"(a), "v"(b));
  return r;
}
__device__ __forceinline__ float fexp2(float x) {
  float r;
  asm("v_exp_f32 %0, %1" : "=v"(r) : "v"(x));
  return r;
}

// ---------------- 1) fused prep: x->bf16  +  W->W^T bf16 ----------------
__global__ __launch_bounds__(256)
void prep_kernel(const float* __restrict__ x, u16* __restrict__ xb,
                 const float* __restrict__ W0, const float* __restrict__ W1,
                 const float* __restrict__ W2, const float* __restrict__ W3,
                 u16* __restrict__ T0, u16* __restrict__ T1,
                 u16* __restrict__ T2, u16* __restrict__ T3) {
  __shared__ float tile[32][33];
  if (blockIdx.x < 4096) {
    const int i = (blockIdx.x * 256 + threadIdx.x) * 4;
    const float4 v = *(const float4*)(x + i);
    uint2 pack;
    pack.x = (uint32_t)f2b(v.x) | ((uint32_t)f2b(v.y) << 16);
    pack.y = (uint32_t)f2b(v.z) | ((uint32_t)f2b(v.w) << 16);
    *(uint2*)(xb + i) = pack;
  } else {
    const int bid2 = blockIdx.x - 4096;
    const float* W; u16* T;
    switch (bid2 >> 10) {
      case 0: W = W0; T = T0; break;
      case 1: W = W1; T = T1; break;
      case 2: W = W2; T = T2; break;
      default: W = W3; T = T3; break;
    }
    const int rem = bid2 & 1023;
    const int n0 = (rem >> 5) * 32, k0 = (rem & 31) * 32;
    const int tx = threadIdx.x & 31, ty = threadIdx.x >> 5;
    #pragma unroll
    for (int i = 0; i < 32; i += 8)
      tile[ty + i][tx] = W[(size_t)(k0 + ty + i) * D_IN + n0 + tx];
    __syncthreads();
    #pragma unroll
    for (int i = 0; i < 32; i += 8)
      T[(size_t)(n0 + ty + i) * D_IN + k0 + tx] = f2b(tile[tx][ty + i]);
  }
}

// ---------------- 2) FUSED QKV projection GEMM (r14, unchanged) ----------------
__device__ __forceinline__ void qkv_compute(
    const u16* __restrict__ AsB, const u16* __restrict__ Bq,
    const u16* __restrict__ Bk, const u16* __restrict__ Bv,
    int wm, int wn, int g, int lm,
    f32x4 accq[4][2], f32x4 acck[4][2], f32x4 accv[4][2]) {
  #pragma unroll
  for (int kk = 0; kk < 2; ++kk) {
    const int slot = ((kk * 4 + g) ^ (lm & 7)) << 3;
    bf16x8 af[4];
    #pragma unroll
    for (int i = 0; i < 4; ++i)
      af[i] = *(const bf16x8*)(AsB + (wm * 64 + i * 16 + lm) * 64 + slot);
    bf16x8 bq[2], bk[2], bv[2];
    #pragma unroll
    for (int n = 0; n < 2; ++n) {
      const int ro = (wn * 32 + n * 16 + lm) * 64 + slot;
      bq[n] = *(const bf16x8*)(Bq + ro);
      bk[n] = *(const bf16x8*)(Bk + ro);
      bv[n] = *(const bf16x8*)(Bv + ro);
    }
    #pragma unroll
    for (int i = 0; i < 4; ++i)
      #pragma unroll
      for (int n = 0; n < 2; ++n) {
        accq[i][n] = __builtin_amdgcn_mfma_f32_16x16x32_bf16(af[i], bq[n], accq[i][n], 0, 0, 0);
        acck[i][n] = __builtin_amdgcn_mfma_f32_16x16x32_bf16(af[i], bk[n], acck[i][n], 0, 0, 0);
        accv[i][n] = __builtin_amdgcn_mfma_f32_16x16x32_bf16(af[i], bv[n], accv[i][n], 0, 0, 0);
      }
  }
}

__global__ __launch_bounds__(512)
void gemm_qkv_kernel(const u16* __restrict__ Xb,
                     const u16* __restrict__ WqT, const u16* __restrict__ WkT,
                     const u16* __restrict__ WvT,
                     u16* __restrict__ Qo, u16* __restrict__ Ko, u16* __restrict__ Vt) {
  __shared__ u16 smem[65536];          // 128 KB: As[2] | Bs[2][3]
  u16* As0 = smem;                     // As[buf] = As0 + buf*8192
  u16* Bs0 = smem + 16384;             // Bs[buf][wh] = Bs0 + buf*24576 + wh*8192

  const int tid = threadIdx.x;
  const int lane = tid & 63;
  const int w = tid >> 6;            // 0..7
  const int wm = w >> 2, wn = w & 3; // wave tile 64x32 per which
  const int bm = blockIdx.x * 128;
  const int bn = blockIdx.y * 128;
  const int g = lane >> 4, lm = lane & 15;

  const int r_in = lane >> 3;
  const int s_w = lane & 7;
  const int swz_col = (s_w ^ r_in) << 3;

  const int c0 = w * 2;  // this wave's chunk base (2 chunks of 8 rows each)
  const u16* a_src0 = Xb + (size_t)(bm + c0 * 8 + r_in) * D_IN + swz_col;
  const u16* a_src1 = a_src0 + 8 * D_IN;
  const u16* q_src0 = WqT + (size_t)(bn + c0 * 8 + r_in) * D_IN + swz_col;
  const u16* q_src1 = q_src0 + 8 * D_IN;
  const u16* k_src0 = WkT + (size_t)(bn + c0 * 8 + r_in) * D_IN + swz_col;
  const u16* k_src1 = k_src0 + 8 * D_IN;
  const u16* v_src0 = WvT + (size_t)(bn + c0 * 8 + r_in) * D_IN + swz_col;
  const u16* v_src1 = v_src0 + 8 * D_IN;

#define QKV_STAGE(BUF, K0)                                            \
  do {                                                                \
    GLD_LDS16(a_src0 + (K0), As0 + (BUF)*8192 + c0 * 512);            \
    GLD_LDS16(a_src1 + (K0), As0 + (BUF)*8192 + c0 * 512 + 512);      \
    GLD_LDS16(q_src0 + (K0), Bs0 + (BUF)*24576 + c0 * 512);           \
    GLD_LDS16(q_src1 + (K0), Bs0 + (BUF)*24576 + c0 * 512 + 512);     \
    GLD_LDS16(k_src0 + (K0), Bs0 + (BUF)*24576 + 8192 + c0 * 512);    \
    GLD_LDS16(k_src1 + (K0), Bs0 + (BUF)*24576 + 8192 + c0 * 512 + 512); \
    GLD_LDS16(v_src0 + (K0), Bs0 + (BUF)*24576 + 16384 + c0 * 512);   \
    GLD_LDS16(v_src1 + (K0), Bs0 + (BUF)*24576 + 16384 + c0 * 512 + 512); \
  } while (0)

  f32x4 accq[4][2], acck[4][2], accv[4][2];
  #pragma unroll
  for (int i = 0; i < 4; ++i)
    #pragma unroll
    for (int n = 0; n < 2; ++n) {
      accq[i][n] = {0.f, 0.f, 0.f, 0.f};
      acck[i][n] = {0.f, 0.f, 0.f, 0.f};
      accv[i][n] = {0.f, 0.f, 0.f, 0.f};
    }

  QKV_STAGE(0, 0);
  QKV_STAGE(1, 64);
  #pragma unroll 1
  for (int tt = 0; tt < 7; ++tt) {
    asm volatile("s_waitcnt vmcnt(8)" ::: "memory");
    __builtin_amdgcn_s_barrier();
    qkv_compute(As0, Bs0, Bs0 + 8192, Bs0 + 16384, wm, wn, g, lm, accq, acck, accv);
    __builtin_amdgcn_s_barrier();
    QKV_STAGE(0, (2 * tt + 2) * 64);
    asm volatile("s_waitcnt vmcnt(8)" ::: "memory");
    __builtin_amdgcn_s_barrier();
    qkv_compute(As0 + 8192, Bs0 + 24576, Bs0 + 32768, Bs0 + 40960, wm, wn, g, lm,
                accq, acck, accv);
    __builtin_amdgcn_s_barrier();
    QKV_STAGE(1, (2 * tt + 3) * 64);
  }
  asm volatile("s_waitcnt vmcnt(8)" ::: "memory");
  __builtin_amdgcn_s_barrier();
  qkv_compute(As0, Bs0, Bs0 + 8192, Bs0 + 16384, wm, wn, g, lm, accq, acck, accv);  // t=14
  asm volatile("s_waitcnt vmcnt(0)" ::: "memory");
  __builtin_amdgcn_s_barrier();
  qkv_compute(As0 + 8192, Bs0 + 24576, Bs0 + 32768, Bs0 + 40960, wm, wn, g, lm,
              accq, acck, accv);  // t=15
#undef QKV_STAGE

  // ---- epilogue: LDS repack -> coalesced fragment stores ----
  __syncthreads();                       // staging LDS now safely reusable
  u16* pool = smem + w * 6144;           // 12 KB per wave: Q[0,2048) K[2048,4096) V[4096,6144)
  const int M0 = bm + wm * 64;
  const int T0v = (M0 & (SEQ - 1)) >> 5; // WITHIN-BATCH tile base (r13 bug fixed)
  const int C0 = bn + wn * 32;
  const int D0 = C0 & 63;                // 0 or 32
  const int S0 = D0 >> 4;                // st base (0 or 2)
  const int d5 = D0 >> 5;                // 0 or 1
  const int bh = (M0 >> 11) * NH + (C0 >> 6);

  #pragma unroll
  for (int i = 0; i < 4; ++i) {
    const int ti = i >> 1;
    const int nbase = (i & 1) * 16 + g * 4;          // nn&31, minus r
    #pragma unroll
    for (int n = 0; n < 2; ++n) {
      #pragma unroll
      for (int r = 0; r < 4; ++r) {
        // Q/K: lane2 = ((d>>3)&1)*32 + (nn&31); j = d&7
        const int offqk = (ti * 2 + n) * 512 + (((lm >> 3) << 5) + nbase + r) * 8 + (lm & 7);
        pool[offqk] = f2b(accq[i][n][r] * QSCL);
        pool[2048 + offqk] = f2b(acck[i][n][r]);
        // V: lane2 = (g&1)*32 + (d&31); j = (g>>1)*4 + r; frag slot = ti*2 + (i&1)
        const int offv = 4096 + (ti * 2 + (i & 1)) * 512 +
                         ((g & 1) * 32 + n * 16 + lm) * 8 + ((g >> 1) << 2) + r;
        pool[offv] = f2b(accv[i][n][r]);
      }
    }
  }
  asm volatile("s_waitcnt lgkmcnt(0)" ::: "memory");
  #pragma unroll
  for (int fl = 0; fl < 4; ++fl) {
    const int t = T0v + (fl >> 1);
    const int st = S0 + (fl & 1);
    const uint4 vq = *(const uint4*)(pool + fl * 512 + lane * 8);
    *(uint4*)(Qo + ((size_t)(bh * 64 + t) * 4 + st) * 512 + lane * 8) = vq;
    const uint4 vk = *(const uint4*)(pool + 2048 + fl * 512 + lane * 8);
    *(uint4*)(Ko + ((size_t)(bh * 64 + t) * 4 + st) * 512 + lane * 8) = vk;
    const int f = ((fl & 1) << 1) + d5;
    const uint4 vv = *(const uint4*)(pool + 4096 + fl * 512 + lane * 8);
    *(uint4*)(Vt + ((size_t)(bh * 64 + t) * 4 + f) * 512 + lane * 8) = vv;
  }
}

// ---------------- 3) causal flash attention: interleaved two-stream ----------------
// 1024 blocks x 4 waves. Block = (bh, jj) handles BOTH q-tiles {jj, 63-jj} in
// ONE k-loop: each wave carries two independent QK->exp->PV streams in the
// causal-overlap region (t <= jj) -> 2x per-wave ILP on the latency chains,
// and one kf/vf fetch feeds both streams (block loads 65 -> 64-jj, -25% avg).
// Wave count UNCHANGED vs r10 (r11's pairing halved waves - that was the
// regression). Single s-chain per stream; fixed softmax max (=0); merge = two
// sequential rounds through one 32 KB mbuf. bid%8==head%8 XCD-pins K/V.
__global__ __launch_bounds__(256)
void attn6_kernel(const u16* __restrict__ Qb, const u16* __restrict__ Kb,
                  const u16* __restrict__ Vt, u16* __restrict__ Ctx) {
  __shared__ float mbuf[4][32][64];   // [wave][q][d], chunk-XOR-swizzled
  __shared__ float lbuf[4][32];

  const int tid = threadIdx.x;
  const int lane = tid & 63;
  const int kw = tid >> 6;             // wave = split-k slot 0..3
  const int ql = lane & 31;
  const int hi = lane >> 5;
  const int bid = blockIdx.x;
  const int c = bid & 7;
  const int r = bid >> 3;              // 0..127
  const int jj = r & 31;               // pair index: q-tiles {jj, 63-jj}
  const int bh = c + 8 * (r >> 5);     // 0..31
  const int b = bh >> 4, h = bh & 15;

  const int qtA = jj;                  // low q-tile (k range 0..qtA)
  const int qtB = 63 - jj;             // high q-tile (k range 0..qtB), qtB > qtA

  const u16* Qf = Qb + (size_t)bh * 64 * 2048;
  const u16* Kf = Kb + (size_t)bh * 64 * 2048;
  const u16* Vf = Vt + (size_t)bh * 64 * 2048;
  const int lofs = lane * 8;

  bf16x8 qfA[4], qfB[4];
  {
    const u16* qpA = Qf + (size_t)qtA * 2048 + lofs;
    const u16* qpB = Qf + (size_t)qtB * 2048 + lofs;
    #pragma unroll
    for (int st = 0; st < 4; ++st) {
      qfA[st] = *(const bf16x8*)(qpA + st * 512);
      qfB[st] = *(const bf16x8*)(qpB + st * 512);
    }
  }

  f32x16 cA0 = {0,0,0,0,0,0,0,0,0,0,0,0,0,0,0,0};
  f32x16 cA1 = {0,0,0,0,0,0,0,0,0,0,0,0,0,0,0,0};
  f32x16 cB0 = {0,0,0,0,0,0,0,0,0,0,0,0,0,0,0,0};
  f32x16 cB1 = {0,0,0,0,0,0,0,0,0,0,0,0,0,0,0,0};
  float lA[2] = {0.f, 0.f};
  float lB[2] = {0.f, 0.f};

  bf16x8 kf[4], vf[4];
  {  // prologue: tile kw (kw <= 3 < 32 <= qtB always)
    const u16* kp = Kf + (size_t)kw * 2048 + lofs;
    const u16* vp = Vf + (size_t)kw * 2048 + lofs;
    #pragma unroll
    for (int st = 0; st < 4; ++st) kf[st] = *(const bf16x8*)(kp + st * 512);
    #pragma unroll
    for (int f = 0; f < 4; ++f) vf[f] = *(const bf16x8*)(vp + f * 512);
  }

  #pragma unroll 1
  for (int t = kw; t <= qtB; t += 4) {
    const int tn = (t + 4 <= qtB) ? (t + 4) : qtB;
    const bool doA = (t <= qtA);

    // ---- stream B (always active) ----
    {
      f32x16 s = {0,0,0,0,0,0,0,0,0,0,0,0,0,0,0,0};
      #pragma unroll
      for (int st = 0; st < 4; ++st)
        s = __builtin_amdgcn_mfma_f32_32x32x16_bf16(kf[st], qfB[st], s, 0, 0, 0);
      float p[16];
      if (t == qtB) {
        #pragma unroll
        for (int cr = 0; cr < 16; ++cr) {
          const int kl = ((cr & 3) + 8 * (cr >> 2)) + 4 * hi;
          p[cr] = (kl > ql) ? 0.f : fexp2(s[cr]);
        }
      } else {
        #pragma unroll
        for (int cr = 0; cr < 16; ++cr) p[cr] = fexp2(s[cr]);
      }
      #pragma unroll
      for (int cr = 0; cr < 16; ++cr) lB[cr & 1] += p[cr];
      #pragma unroll
      for (int ks = 0; ks < 2; ++ks) {
        uint4 pw;
        pw.x = cvtpk(p[ks * 8 + 0], p[ks * 8 + 1]);
        pw.y = cvtpk(p[ks * 8 + 2], p[ks * 8 + 3]);
        pw.z = cvtpk(p[ks * 8 + 4], p[ks * 8 + 5]);
        pw.w = cvtpk(p[ks * 8 + 6], p[ks * 8 + 7]);
        union { uint4 u; bf16x8 v; } pa; pa.u = pw;
        cB0 = __builtin_amdgcn_mfma_f32_32x32x16_bf16(vf[ks * 2 + 0], pa.v, cB0, 0, 0, 0);
        cB1 = __builtin_amdgcn_mfma_f32_32x32x16_bf16(vf[ks * 2 + 1], pa.v, cB1, 0, 0, 0);
      }
    }

    // ---- stream A (causal-overlap region) ----
    if (doA) {
      f32x16 s = {0,0,0,0,0,0,0,0,0,0,0,0,0,0,0,0};
      #pragma unroll
      for (int st = 0; st < 4; ++st)
        s = __builtin_amdgcn_mfma_f32_32x32x16_bf16(kf[st], qfA[st], s, 0, 0, 0);
      // prefetch next K (kf dead after both QKs)
      {
        const u16* kp = Kf + (size_t)tn * 2048 + lofs;
        #pragma unroll
        for (int st = 0; st < 4; ++st) kf[st] = *(const bf16x8*)(kp + st * 512);
      }
      float p[16];
      if (t == qtA) {
        #pragma unroll
        for (int cr = 0; cr < 16; ++cr) {
          const int kl = ((cr & 3) + 8 * (cr >> 2)) + 4 * hi;
          p[cr] = (kl > ql) ? 0.f : fexp2(s[cr]);
        }
      } else {
        #pragma unroll
        for (int cr = 0; cr < 16; ++cr) p[cr] = fexp2(s[cr]);
      }
      #pragma unroll
      for (int cr = 0; cr < 16; ++cr) lA[cr & 1] += p[cr];
      #pragma unroll
      for (int ks = 0; ks < 2; ++ks) {
        uint4 pw;
        pw.x = cvtpk(p[ks * 8 + 0], p[ks * 8 + 1]);
        pw.y = cvtpk(p[ks * 8 + 2], p[ks * 8 + 3]);
        pw.z = cvtpk(p[ks * 8 + 4], p[ks * 8 + 5]);
        pw.w = cvtpk(p[ks * 8 + 6], p[ks * 8 + 7]);
        union { uint4 u; bf16x8 v; } pa; pa.u = pw;
        cA0 = __builtin_amdgcn_mfma_f32_32x32x16_bf16(vf[ks * 2 + 0], pa.v, cA0, 0, 0, 0);
        cA1 = __builtin_amdgcn_mfma_f32_32x32x16_bf16(vf[ks * 2 + 1], pa.v, cA1, 0, 0, 0);
      }
    } else {
      // B-only region: prefetch K here (kf dead after B's QK)
      const u16* kp = Kf + (size_t)tn * 2048 + lofs;
      #pragma unroll
      for (int st = 0; st < 4; ++st) kf[st] = *(const bf16x8*)(kp + st * 512);
    }

    // prefetch next V (vf dead after all PVs this iteration)
    {
      const u16* vp = Vf + (size_t)tn * 2048 + lofs;
      #pragma unroll
      for (int f = 0; f < 4; ++f) vf[f] = *(const bf16x8*)(vp + f * 512);
    }
  }

  // ---- merge round A, then round B (shared mbuf, fixed max -> pure addition) ----
  #pragma unroll
  for (int round = 0; round < 2; ++round) {
    const f32x16& x0 = round ? cB0 : cA0;
    const f32x16& x1 = round ? cB1 : cA1;
    const float ll = round ? (lB[0] + lB[1]) : (lA[0] + lA[1]);
    const float lwv = ll + swap32f(ll);
    const int qt = round ? qtB : qtA;

    if (round) __syncthreads();  // all reads of round-A mbuf done
    #pragma unroll
    for (int grp = 0; grp < 4; ++grp) {
      const int ch = grp * 2 + hi;
      f32x4 t0 = {x0[grp * 4 + 0], x0[grp * 4 + 1], x0[grp * 4 + 2], x0[grp * 4 + 3]};
      f32x4 t1 = {x1[grp * 4 + 0], x1[grp * 4 + 1], x1[grp * 4 + 2], x1[grp * 4 + 3]};
      *(f32x4*)&mbuf[kw][ql][(ch ^ ql) * 4 & 63]       = t0;
      *(f32x4*)&mbuf[kw][ql][((ch + 8) ^ ql) * 4 & 63] = t1;
    }
    if (lane < 32) lbuf[kw][ql] = lwv;
    __syncthreads();

    {
      const int ch0 = kw * 4 + hi * 2;
      f32x4 a0 = {0.f, 0.f, 0.f, 0.f}, a1 = {0.f, 0.f, 0.f, 0.f};
      #pragma unroll
      for (int p2 = 0; p2 < 4; ++p2) {
        a0 += *(const f32x4*)&mbuf[p2][ql][(ch0 ^ ql) * 4 & 63];
        a1 += *(const f32x4*)&mbuf[p2][ql][((ch0 + 1) ^ ql) * 4 & 63];
      }
      const float lt = (lbuf[0][ql] + lbuf[1][ql]) + (lbuf[2][ql] + lbuf[3][ql]);
      const float inv = __builtin_amdgcn_rcpf(lt);
      uint4 pw;
      pw.x = cvtpk(a0[0] * inv, a0[1] * inv);
      pw.y = cvtpk(a0[2] * inv, a0[3] * inv);
      pw.z = cvtpk(a1[0] * inv, a1[1] * inv);
      pw.w = cvtpk(a1[2] * inv, a1[3] * inv);
      *(uint4*)(Ctx + (size_t)(b * SEQ + qt * 32 + ql) * 1024 + h * 64 + kw * 16 + hi * 8) = pw;
    }
  }
}

// ---------------- 4) output projection + bias (fp32 out; r15, unchanged) ----------------
__device__ __forceinline__ void out_compute(
    const u16* __restrict__ AsB, const u16* __restrict__ BsB,
    int wr, int wc, int g, int lm, f32x4 acc[2][4]) {
  #pragma unroll
  for (int kk = 0; kk < 2; ++kk) {
    const int slot = ((kk * 4 + g) ^ (lm & 7)) << 3;
    bf16x8 af[2], bf[4];
    #pragma unroll
    for (int i = 0; i < 2; ++i)
      af[i] = *(const bf16x8*)(AsB + (wr * 32 + i * 16 + lm) * 64 + slot);
    #pragma unroll
    for (int n = 0; n < 4; ++n)
      bf[n] = *(const bf16x8*)(BsB + (wc * 64 + n * 16 + lm) * 64 + slot);
    #pragma unroll
    for (int i = 0; i < 2; ++i)
      #pragma unroll
      for (int n = 0; n < 4; ++n)
        acc[i][n] = __builtin_amdgcn_mfma_f32_16x16x32_bf16(af[i], bf[n], acc[i][n], 0, 0, 0);
  }
}

__global__ __launch_bounds__(256)
void gemm_out_kernel(const u16* __restrict__ Ctx, const u16* __restrict__ WoT,
                     const float* __restrict__ bo, float* __restrict__ out) {
  __shared__ u16 As[2][64 * 64];   // 8 KB each
  __shared__ u16 Bs[2][128 * 64];  // 16 KB each
  const int tid = threadIdx.x;
  const int lane = tid & 63;
  const int w = tid >> 6;
  const int bm = blockIdx.x * 64;
  const int bn = blockIdx.y * 128;
  const int wr = w >> 1, wc = w & 1;
  const int g = lane >> 4, lm = lane & 15;

  const int r_in = lane >> 3;
  const int s_w = lane & 7;
  const int swz_col = (s_w ^ r_in) << 3;

  const u16* a_src = Ctx + (size_t)(bm + w * 16 + r_in) * D_IN + swz_col;
  const u16* b_src = WoT + (size_t)(bn + w * 32 + r_in) * D_IN + swz_col;

#define OUT_STAGE(BUF, K0)                                                  \
  do {                                                                      \
    GLD_LDS16(a_src + (K0), &As[BUF][(w * 2) * 512]);                       \
    GLD_LDS16(a_src + 8 * D_IN + (K0), &As[BUF][(w * 2 + 1) * 512]);        \
    _Pragma("unroll")                                                       \
    for (int j = 0; j < 4; ++j)                                             \
      GLD_LDS16(b_src + j * 8 * D_IN + (K0), &Bs[BUF][(w * 4 + j) * 512]);  \
  } while (0)

  f32x4 acc[2][4];
  #pragma unroll
  for (int i = 0; i < 2; ++i)
    #pragma unroll
    for (int n = 0; n < 4; ++n) acc[i][n] = {0.f, 0.f, 0.f, 0.f};

  OUT_STAGE(0, 0);
  OUT_STAGE(1, 64);
  #pragma unroll 1
  for (int tt = 0; tt < 7; ++tt) {
    asm volatile("s_waitcnt vmcnt(6)" ::: "memory");
    __builtin_amdgcn_s_barrier();
    out_compute(As[0], Bs[0], wr, wc, g, lm, acc);
    __builtin_amdgcn_s_barrier();
    OUT_STAGE(0, (2 * tt + 2) * 64);
    asm volatile("s_waitcnt vmcnt(6)" ::: "memory");
    __builtin_amdgcn_s_barrier();
    out_compute(As[1], Bs[1], wr, wc, g, lm, acc);
    __builtin_amdgcn_s_barrier();
    OUT_STAGE(1, (2 * tt + 3) * 64);
  }
  asm volatile("s_waitcnt vmcnt(6)" ::: "memory");
  __builtin_amdgcn_s_barrier();
  out_compute(As[0], Bs[0], wr, wc, g, lm, acc);  // t=14
  asm volatile("s_waitcnt vmcnt(0)" ::: "memory");
  __builtin_amdgcn_s_barrier();
  out_compute(As[1], Bs[1], wr, wc, g, lm, acc);  // t=15
#undef OUT_STAGE

  #pragma unroll
  for (int i = 0; i < 2; ++i)
    #pragma unroll
    for (int n = 0; n < 4; ++n)
      #pragma unroll
      for (int r = 0; r < 4; ++r) {
        const int m = bm + wr * 32 + i * 16 + g * 4 + r;
        const int cidx = bn + wc * 64 + n * 16 + lm;
        out[(size_t)m * 1024 + cidx] = acc[i][n][r] + bo[cidx];
      }
}

extern "C" void kernel_launch(void* const* d_in, const int* in_sizes, int n_in,
                              void* d_out, int out_size, void* d_ws, size_t ws_size,
                              hipStream_t stream) {
  (void)in_sizes; (void)n_in; (void)out_size; (void)ws_size;
  const float* x  = (const float*)d_in[0];
  const float* Wq = (const float*)d_in[1];
  const float* Wk = (const float*)d_in[2];
  const float* Wv = (const float*)d_in[3];
  const float* Wo = (const float*)d_in[4];
  const float* bo = (const float*)d_in[5];
  float* out = (float*)d_out;

  char* ws = (char*)d_ws;
  u16* xb  = (u16*)(ws);
  u16* WqT = (u16*)(ws + (8u << 20));
  u16* WkT = (u16*)(ws + (10u << 20));
  u16* WvT = (u16*)(ws + (12u << 20));
  u16* WoT = (u16*)(ws + (14u << 20));
  u16* Qb  = (u16*)(ws + (16u << 20));
  u16* Kb  = (u16*)(ws + (24u << 20));
  u16* Vt  = (u16*)(ws + (32u << 20));
  u16* Ctx = xb;  // xb fully consumed by gemm_qkv before attn writes Ctx

  prep_kernel<<<dim3(8192), 256, 0, stream>>>(x, xb, Wq, Wk, Wv, Wo, WqT, WkT, WvT, WoT);
  gemm_qkv_kernel<<<dim3(32, 8), 512, 0, stream>>>(xb, WqT, WkT, WvT, Qb, Kb, Vt);
  attn6_kernel<<<dim3(1024), 256, 0, stream>>>(Qb, Kb, Vt, Ctx);
  gemm_out_kernel<<<dim3(64, 8), 256, 0, stream>>>(Ctx, WoT, bo, out);
}